// Round 11
// baseline (12020.208 us; speedup 1.0000x reference)
//
#include <hip/hip_runtime.h>
#include <hip/hip_bf16.h>

// ScannedRNN: 2-cell LayerNorm-GRU scan. T=512, B=128, H=512.
// Reset-bucketed rounds, cell0/cell1 split, NT streaming hints.
// R11: B-loads restructured for SGPR-base addressing -- per-wave weight
// panel base made wave-uniform (readfirstlane), 16 per-ct base pointers
// hoisted out of the kb loop (SGPR pairs), single shared VGPR offset.
// Goal: compiler emits 16 back-to-back global_load_dwordx4 (16 in flight)
// instead of load->wait->mfma serialization (measured ~1 in flight).

#define TT 512
#define BB 128
#define HH 512
#define RCAP 20
#define FLAG_WORD 32768

typedef __attribute__((ext_vector_type(8))) short short8;
typedef __attribute__((ext_vector_type(4))) float f32x4;
typedef unsigned int u32;

__device__ __forceinline__ short f2bf(float f) {
  unsigned u = __float_as_uint(f);
  unsigned r = (u + 0x7fffu + ((u >> 16) & 1u)) >> 16;
  return (short)r;
}
__device__ __forceinline__ float bf2f(short s) {
  return __uint_as_float(((unsigned)(unsigned short)s) << 16);
}
__device__ __forceinline__ float sigf(float x) { return 1.f / (1.f + __expf(-x)); }
__device__ __forceinline__ f32x4 ldnt4(const float* p) {
  return __builtin_nontemporal_load((const f32x4*)p);
}
__device__ __forceinline__ void stnt(float* p, float v) {
  __builtin_nontemporal_store(v, p);
}

// tiled weight index: W0 (K=1024): tile=(col>>4)*32+(k>>5); W1 (K=512): (col>>4)*16+(k>>5)
__device__ __forceinline__ size_t w0idx(int col, int k) {
  return (size_t)((col >> 4) * 32 + (k >> 5)) * 512 + (col & 15) * 32 + (k & 31);
}
__device__ __forceinline__ size_t w1idx(int col, int k) {
  return (size_t)((col >> 4) * 16 + (k >> 5)) * 512 + (col & 15) * 32 + (k & 31);
}

// ---------------- pack: weights f32 -> bf16, TILED layout ----------------
__global__ void pack_kernel(const float* __restrict__ Wi, const float* __restrict__ Wh_rz,
                            const float* __restrict__ Wh_n, const void* __restrict__ resets,
                            short* __restrict__ W0p, short* __restrict__ W1p,
                            unsigned* __restrict__ cnt) {
  int gid = blockIdx.x * 256 + threadIdx.x;
  if (gid == 0) {
    const unsigned char* rb = (const unsigned char*)resets;
    unsigned intmode = 1u;
    for (int i = 1; i < 4096; ++i) {
      if ((i & 3) && rb[i]) { intmode = 0u; break; }
    }
    cnt[FLAG_WORD] = intmode;
  }
  const int n0 = 2048 * 128;
  const int n1 = 2048 * 64;
  if (gid < n0) {
    int col = gid & 2047, kb = (gid >> 11) * 8;
    int reg = col >> 9, j = col & 511;
    short8 o;
#pragma unroll
    for (int i = 0; i < 8; ++i) {
      int k = kb + i; float v;
      if (reg == 0)      v = (k < 512) ? Wi[(size_t)k * 1536 + j]        : Wh_rz[(size_t)(k - 512) * 1024 + j];
      else if (reg == 1) v = (k < 512) ? Wi[(size_t)k * 1536 + 512 + j]  : Wh_rz[(size_t)(k - 512) * 1024 + 512 + j];
      else if (reg == 2) v = (k < 512) ? Wi[(size_t)k * 1536 + 1024 + j] : 0.f;
      else               v = (k < 512) ? 0.f                             : Wh_n[(size_t)(k - 512) * 512 + j];
      o[i] = f2bf(v);
    }
    *(short8*)&W0p[w0idx(col, kb)] = o;
  } else if (gid < n0 + n1) {
    int g = gid - n0;
    int col = g & 2047, kb = (g >> 11) * 8;
    int reg = col >> 9, j = col & 511;
    const float* Wi1  = Wi + (size_t)512 * 1536;
    const float* Wrz1 = Wh_rz + (size_t)512 * 1024;
    const float* Wn1  = Wh_n + (size_t)512 * 512;
    short8 o;
#pragma unroll
    for (int i = 0; i < 8; ++i) {
      int k = kb + i; float v;
      if (reg == 0)      v = Wi1[(size_t)k * 1536 + j] + Wrz1[(size_t)k * 1024 + j];
      else if (reg == 1) v = Wi1[(size_t)k * 1536 + 512 + j] + Wrz1[(size_t)k * 1024 + 512 + j];
      else if (reg == 2) v = Wi1[(size_t)k * 1536 + 1024 + j];
      else               v = Wn1[(size_t)k * 512 + j];
      o[i] = f2bf(v);
    }
    *(short8*)&W1p[w1idx(col, kb)] = o;
  }
}

// ---------------- prep: bucket cells by d (single WG) ----------------
__global__ void prep_kernel(const void* __restrict__ resets, unsigned* __restrict__ cnt,
                            u32* __restrict__ bucket) {
  __shared__ u32 hist[RCAP + 1];
  __shared__ u32 cur[RCAP + 1];
  const int tid = threadIdx.x;
  const int rmode = (int)cnt[FLAG_WORD];
  const unsigned char* r8 = (const unsigned char*)resets;
  const int* r32 = (const int*)resets;
  if (tid <= RCAP) hist[tid] = 0;
  __syncthreads();
  if (tid < BB) {
    int d = 0;
    for (int t = 0; t < TT; ++t) {
      bool rs = rmode ? (r32[t * BB + tid] != 0) : (r8[t * BB + tid] != 0);
      d = (t == 0 || rs) ? 0 : d + 1;
      int dd = d < RCAP ? d : RCAP;
      atomicAdd(&hist[dd], 1u);
    }
  }
  __syncthreads();
  if (tid == 0) {
    u32 acc = 0;
    for (int i = 0; i <= RCAP; ++i) { u32 h = hist[i]; cur[i] = acc; cnt[i] = acc; acc += h; }
  }
  __syncthreads();
  if (tid < BB) {
    int d = 0;
    for (int t = 0; t < TT; ++t) {
      bool rs = rmode ? (r32[t * BB + tid] != 0) : (r8[t * BB + tid] != 0);
      d = (t == 0 || rs) ? 0 : d + 1;
      if (d < RCAP) {
        u32 pos = atomicAdd(&cur[d], 1u);
        bucket[pos] = ((u32)t << 7) | (u32)tid;
      }
    }
  }
}

// ---------------- round_a: cell0 for bucket tau -> h1 (f32) into ys[t,b] ----------------
__global__ __launch_bounds__(512, 1) void round_a(
    int tau, const float* __restrict__ ins, const void* __restrict__ resets,
    const float* __restrict__ h0, const float* __restrict__ bi,
    const float* __restrict__ bh_n, const float* __restrict__ ln_s,
    const float* __restrict__ ln_b, const short* __restrict__ W0p,
    const unsigned* __restrict__ cnt, const u32* __restrict__ bucket,
    float* __restrict__ out) {
  __shared__ short lds[81920];          // 160 KB
  short* A0 = lds;                      // [32][1024] bf16, xor-swizzled rows
  short* RB = lds + 32768;              // [32][512] r-gate
  short* ZB = lds + 49152;              // [32][512] z-gate
  short* HB = lds + 65536;              // [32][512] hn
  float* st0 = (float*)lds;             // 256 f32 stats (row0 ins area, dead after GEMM)

  const int tid = threadIdx.x;
  const int l = tid & 63, wv = tid >> 6, c16 = l & 15, kc = l >> 4;
  const int gate = wv >> 1, half = wv & 1;
  const int rmode = (int)cnt[FLAG_WORD];
  const u32 boff = cnt[tau];
  const u32 M = cnt[tau + 1] - boff;
  float* ys = out + BB * HH;
  const int sw0 = (c16 & 7) << 3;
  const int lane16 = c16 * 32 + kc * 8;

  // wave-uniform weight-panel base (SGPR) + hoisted per-ct bases (SGPR pairs)
  const int wv_u = __builtin_amdgcn_readfirstlane(wv);
  const short* __restrict__ wpanel = W0p + (size_t)wv_u * (16 * 32 * 512);
  const short* bctp[16];
#pragma unroll
  for (int ct = 0; ct < 16; ++ct) bctp[ct] = wpanel + ct * (32 * 512);

  for (u32 g = blockIdx.x; g * 32 < M; g += gridDim.x) {
    const u32 gb = boff + g * 32;
    __syncthreads();

    // ---- stage A0: row = [ins(t,b) | h_in] bf16, swizzled; NT loads ----
    {
      const int row = tid >> 4, part = tid & 15;
      const u32 m = g * 32 + (u32)row;
      u32 e = (m < M) ? bucket[gb + row] : 0xFFFFFFFFu;
      const int t = (int)((e >> 7) & 511), b = (int)(e & 127);
      const int sw = (row & 7) << 3;
      if (e == 0xFFFFFFFFu) {
        const int k0 = part * 64;
        short8 z = {};
#pragma unroll
        for (int gg = 0; gg < 8; ++gg)
          *(short8*)&A0[row * 1024 + ((k0 + gg * 8) ^ sw)] = z;
      } else if (part < 8) {            // ins half
        const int k0 = part * 64;
        const float* src = ins + (size_t)t * (BB * HH) + (size_t)b * HH + k0;
#pragma unroll
        for (int gg = 0; gg < 8; ++gg) {
          f32x4 u0 = ldnt4(src + gg * 8);
          f32x4 u1 = ldnt4(src + gg * 8 + 4);
          short8 v;
          v[0] = f2bf(u0.x); v[1] = f2bf(u0.y); v[2] = f2bf(u0.z); v[3] = f2bf(u0.w);
          v[4] = f2bf(u1.x); v[5] = f2bf(u1.y); v[6] = f2bf(u1.z); v[7] = f2bf(u1.w);
          *(short8*)&A0[row * 1024 + ((k0 + gg * 8) ^ sw)] = v;
        }
      } else {                          // h half
        const int k0 = (part - 8) * 64;
        const float* src = nullptr;
        bool zero = false;
        if (tau > 0) {
          src = ys + (size_t)(t - 1) * (BB * HH) + (size_t)b * HH + k0;
        } else {
          bool rs = rmode ? (((const int*)resets)[t * BB + b] != 0)
                          : (((const unsigned char*)resets)[t * BB + b] != 0);
          if (rs) zero = true; else src = h0 + (size_t)b * HH + k0;  // t==0 here
        }
#pragma unroll
        for (int gg = 0; gg < 8; ++gg) {
          short8 v = {};
          if (!zero) {
            f32x4 u0 = ldnt4(src + gg * 8);
            f32x4 u1 = ldnt4(src + gg * 8 + 4);
            v[0] = f2bf(u0.x); v[1] = f2bf(u0.y); v[2] = f2bf(u0.z); v[3] = f2bf(u0.w);
            v[4] = f2bf(u1.x); v[5] = f2bf(u1.y); v[6] = f2bf(u1.z); v[7] = f2bf(u1.w);
          }
          *(short8*)&A0[row * 1024 + ((512 + k0 + gg * 8) ^ sw)] = v;
        }
      }
    }
    __syncthreads();

    // ---- cell0 GEMM: 16 loads per kb grouped via SGPR-base + shared voff ----
    f32x4 acc[2][16];
#pragma unroll
    for (int rt = 0; rt < 2; ++rt)
#pragma unroll
      for (int ct = 0; ct < 16; ++ct) acc[rt][ct] = (f32x4){0.f, 0.f, 0.f, 0.f};
    {
      const int kb_lo = (gate == 3) ? 16 : 0;
      const int kb_hi = (gate == 2) ? 16 : 32;
#pragma unroll 1
      for (int kb = kb_lo; kb < kb_hi; ++kb) {
        const int voff = kb * 512 + lane16;   // element offset, per-lane VGPR
        short8 bq[16];
#pragma unroll
        for (int ct = 0; ct < 16; ++ct)
          bq[ct] = *(const short8*)(bctp[ct] + voff);
        const int k = kb * 32 + kc * 8;
        short8 a0 = *(const short8*)&A0[c16 * 1024 + (k ^ sw0)];
        short8 a1 = *(const short8*)&A0[(16 + c16) * 1024 + (k ^ sw0)];
#pragma unroll
        for (int ct = 0; ct < 16; ++ct) {
          acc[0][ct] = __builtin_amdgcn_mfma_f32_16x16x32_bf16(a0, bq[ct], acc[0][ct], 0, 0, 0);
          acc[1][ct] = __builtin_amdgcn_mfma_f32_16x16x32_bf16(a1, bq[ct], acc[1][ct], 0, 0, 0);
        }
      }
    }
    __syncthreads();

    // ---- bias + LN stats ----
#pragma unroll
    for (int ct = 0; ct < 16; ++ct) {
      const int col = wv * 256 + ct * 16 + c16;
      const int j = col & 511;
      float bs = (gate == 3) ? bh_n[j] : bi[col];
#pragma unroll
      for (int rt = 0; rt < 2; ++rt)
#pragma unroll
        for (int rr = 0; rr < 4; ++rr) acc[rt][ct][rr] += bs;
    }
    if (gate < 2) {
#pragma unroll
      for (int rt = 0; rt < 2; ++rt)
#pragma unroll
        for (int rr = 0; rr < 4; ++rr) {
          float s = 0.f, q = 0.f;
#pragma unroll
          for (int ct = 0; ct < 16; ++ct) { float v = acc[rt][ct][rr]; s += v; q += v * v; }
#pragma unroll
          for (int o = 8; o >= 1; o >>= 1) { s += __shfl_xor(s, o); q += __shfl_xor(q, o); }
          if (c16 == 0) {
            const int row = rt * 16 + kc * 4 + rr;
            st0[gate * 128 + row * 4 + half * 2 + 0] = s;
            st0[gate * 128 + row * 4 + half * 2 + 1] = q;
          }
        }
    }
    __syncthreads();

    // ---- gates ----
    if (gate < 2) {
#pragma unroll
      for (int rt = 0; rt < 2; ++rt)
#pragma unroll
        for (int rr = 0; rr < 4; ++rr) {
          const int row = rt * 16 + kc * 4 + rr;
          float S = st0[gate * 128 + row * 4 + 0] + st0[gate * 128 + row * 4 + 2];
          float Q = st0[gate * 128 + row * 4 + 1] + st0[gate * 128 + row * 4 + 3];
          float m = S * (1.f / 512.f);
          float vv = Q * (1.f / 512.f) - m * m;
          float ir = rsqrtf(vv + 1e-6f);
#pragma unroll
          for (int ct = 0; ct < 16; ++ct) {
            const int col = wv * 256 + ct * 16 + c16;
            const int j = col & 511;
            float gv = sigf((acc[rt][ct][rr] - m) * ir * ln_s[gate * 512 + j] + ln_b[gate * 512 + j]);
            ((gate == 0) ? RB : ZB)[row * 512 + j] = f2bf(gv);
          }
        }
    } else if (gate == 3) {
#pragma unroll
      for (int rt = 0; rt < 2; ++rt)
#pragma unroll
        for (int rr = 0; rr < 4; ++rr) {
          const int row = rt * 16 + kc * 4 + rr;
#pragma unroll
          for (int ct = 0; ct < 16; ++ct) {
            const int j = (wv * 256 + ct * 16 + c16) & 511;
            HB[row * 512 + j] = f2bf(acc[rt][ct][rr]);
          }
        }
    }
    __syncthreads();

    // ---- combine (gate2 holds xn): h1 -> ys[t,b] (f32, NT store) ----
    if (gate == 2) {
#pragma unroll
      for (int rt = 0; rt < 2; ++rt)
#pragma unroll
        for (int rr = 0; rr < 4; ++rr) {
          const int row = rt * 16 + kc * 4 + rr;
          const int sw = (row & 7) << 3;
          const u32 m = g * 32 + (u32)row;
          if (m >= M) continue;
          const u32 e = bucket[gb + row];
          const int t = (int)((e >> 7) & 511), b = (int)(e & 127);
          float* yrow = ys + (size_t)t * (BB * HH) + (size_t)b * HH;
#pragma unroll
          for (int ct = 0; ct < 16; ++ct) {
            const int j = (wv * 256 + ct * 16 + c16) & 511;
            float r = bf2f(RB[row * 512 + j]);
            float z = bf2f(ZB[row * 512 + j]);
            float hn = bf2f(HB[row * 512 + j]);
            float hin = bf2f(A0[row * 1024 + ((512 + j) ^ sw)]);
            float h1 = (1.f - z) * tanhf(acc[rt][ct][rr] + r * hn) + z * hin;
            stnt(&yrow[j], h1);
          }
        }
    }
    __syncthreads();
  }
}

// ---------------- round_b: cell1 for bucket tau; h1 from ys -> h2 ----------------
__global__ __launch_bounds__(512, 1) void round_b(
    int tau, const float* __restrict__ bi, const float* __restrict__ bh_n,
    const float* __restrict__ ln_s, const float* __restrict__ ln_b,
    const short* __restrict__ W1p, const unsigned* __restrict__ cnt,
    const u32* __restrict__ bucket, float* __restrict__ out) {
  __shared__ short lds[66560];          // 130 KB
  short* A1 = lds;                      // [32][512] bf16 h1, swizzled
  short* RB = lds + 16384;
  short* ZB = lds + 32768;
  short* HB = lds + 49152;
  float* st1 = (float*)(lds + 65536);   // 256 f32 stats

  const int tid = threadIdx.x;
  const int l = tid & 63, wv = tid >> 6, c16 = l & 15, kc = l >> 4;
  const int gate = wv >> 1, half = wv & 1;
  const u32 boff = cnt[tau];
  const u32 M = cnt[tau + 1] - boff;
  float* ys = out + BB * HH;
  const int sw0 = (c16 & 7) << 3;
  const int lane16 = c16 * 32 + kc * 8;

  const int wv_u = __builtin_amdgcn_readfirstlane(wv);
  const short* __restrict__ wpanel = W1p + (size_t)wv_u * (16 * 16 * 512);
  const short* bctp[16];
#pragma unroll
  for (int ct = 0; ct < 16; ++ct) bctp[ct] = wpanel + ct * (16 * 512);

  for (u32 g = blockIdx.x; g * 32 < M; g += gridDim.x) {
    const u32 gb = boff + g * 32;
    __syncthreads();

    // ---- stage A1: h1 from ys[t,b] (NT load, f32 -> bf16, swizzled) ----
    {
      const int row = tid >> 4, part = tid & 15;
      const u32 m = g * 32 + (u32)row;
      u32 e = (m < M) ? bucket[gb + row] : 0xFFFFFFFFu;
      const int t = (int)((e >> 7) & 511), b = (int)(e & 127);
      const int sw = (row & 7) << 3;
      const int k0 = part * 32;
      if (e == 0xFFFFFFFFu) {
        short8 z = {};
#pragma unroll
        for (int gg = 0; gg < 4; ++gg)
          *(short8*)&A1[row * 512 + ((k0 + gg * 8) ^ sw)] = z;
      } else {
        const float* src = ys + (size_t)t * (BB * HH) + (size_t)b * HH + k0;
#pragma unroll
        for (int gg = 0; gg < 4; ++gg) {
          f32x4 u0 = ldnt4(src + gg * 8);
          f32x4 u1 = ldnt4(src + gg * 8 + 4);
          short8 v;
          v[0] = f2bf(u0.x); v[1] = f2bf(u0.y); v[2] = f2bf(u0.z); v[3] = f2bf(u0.w);
          v[4] = f2bf(u1.x); v[5] = f2bf(u1.y); v[6] = f2bf(u1.z); v[7] = f2bf(u1.w);
          *(short8*)&A1[row * 512 + ((k0 + gg * 8) ^ sw)] = v;
        }
      }
    }
    __syncthreads();

    // ---- cell1 GEMM: grouped B-loads ----
    f32x4 acc[2][16];
#pragma unroll
    for (int rt = 0; rt < 2; ++rt)
#pragma unroll
      for (int ct = 0; ct < 16; ++ct) acc[rt][ct] = (f32x4){0.f, 0.f, 0.f, 0.f};
#pragma unroll 1
    for (int kb = 0; kb < 16; ++kb) {
      const int voff = kb * 512 + lane16;
      short8 bq[16];
#pragma unroll
      for (int ct = 0; ct < 16; ++ct)
        bq[ct] = *(const short8*)(bctp[ct] + voff);
      const int k = kb * 32 + kc * 8;
      short8 a0 = *(const short8*)&A1[c16 * 512 + (k ^ sw0)];
      short8 a1 = *(const short8*)&A1[(16 + c16) * 512 + (k ^ sw0)];
#pragma unroll
      for (int ct = 0; ct < 16; ++ct) {
        acc[0][ct] = __builtin_amdgcn_mfma_f32_16x16x32_bf16(a0, bq[ct], acc[0][ct], 0, 0, 0);
        acc[1][ct] = __builtin_amdgcn_mfma_f32_16x16x32_bf16(a1, bq[ct], acc[1][ct], 0, 0, 0);
      }
    }
    __syncthreads();

    // ---- bias + stats ----
#pragma unroll
    for (int ct = 0; ct < 16; ++ct) {
      const int col = wv * 256 + ct * 16 + c16;
      const int j = col & 511;
      float bs = (gate == 3) ? bh_n[512 + j] : bi[1536 + col];
#pragma unroll
      for (int rt = 0; rt < 2; ++rt)
#pragma unroll
        for (int rr = 0; rr < 4; ++rr) acc[rt][ct][rr] += bs;
    }
    if (gate < 2) {
#pragma unroll
      for (int rt = 0; rt < 2; ++rt)
#pragma unroll
        for (int rr = 0; rr < 4; ++rr) {
          float s = 0.f, q = 0.f;
#pragma unroll
          for (int ct = 0; ct < 16; ++ct) { float v = acc[rt][ct][rr]; s += v; q += v * v; }
#pragma unroll
          for (int o = 8; o >= 1; o >>= 1) { s += __shfl_xor(s, o); q += __shfl_xor(q, o); }
          if (c16 == 0) {
            const int row = rt * 16 + kc * 4 + rr;
            st1[gate * 128 + row * 4 + half * 2 + 0] = s;
            st1[gate * 128 + row * 4 + half * 2 + 1] = q;
          }
        }
    }
    __syncthreads();

    // ---- gates ----
    if (gate < 2) {
#pragma unroll
      for (int rt = 0; rt < 2; ++rt)
#pragma unroll
        for (int rr = 0; rr < 4; ++rr) {
          const int row = rt * 16 + kc * 4 + rr;
          float S = st1[gate * 128 + row * 4 + 0] + st1[gate * 128 + row * 4 + 2];
          float Q = st1[gate * 128 + row * 4 + 1] + st1[gate * 128 + row * 4 + 3];
          float m = S * (1.f / 512.f);
          float vv = Q * (1.f / 512.f) - m * m;
          float ir = rsqrtf(vv + 1e-6f);
#pragma unroll
          for (int ct = 0; ct < 16; ++ct) {
            const int col = wv * 256 + ct * 16 + c16;
            const int j = col & 511;
            float gv = sigf((acc[rt][ct][rr] - m) * ir * ln_s[1024 + gate * 512 + j] +
                            ln_b[1024 + gate * 512 + j]);
            ((gate == 0) ? RB : ZB)[row * 512 + j] = f2bf(gv);
          }
        }
    } else if (gate == 3) {
#pragma unroll
      for (int rt = 0; rt < 2; ++rt)
#pragma unroll
        for (int rr = 0; rr < 4; ++rr) {
          const int row = rt * 16 + kc * 4 + rr;
#pragma unroll
          for (int ct = 0; ct < 16; ++ct) {
            const int j = (wv * 256 + ct * 16 + c16) & 511;
            HB[row * 512 + j] = f2bf(acc[rt][ct][rr]);
          }
        }
    }
    __syncthreads();

    // ---- combine -> h2 -> ys[t,b] (+out at t=511), NT stores ----
    if (gate == 2) {
#pragma unroll
      for (int rt = 0; rt < 2; ++rt)
#pragma unroll
        for (int rr = 0; rr < 4; ++rr) {
          const int row = rt * 16 + kc * 4 + rr;
          const int sw = (row & 7) << 3;
          const u32 m = g * 32 + (u32)row;
          if (m >= M) continue;
          const u32 e = bucket[gb + row];
          const int t = (int)((e >> 7) & 511), b = (int)(e & 127);
          float* yrow = ys + (size_t)t * (BB * HH) + (size_t)b * HH;
#pragma unroll
          for (int ct = 0; ct < 16; ++ct) {
            const int j = (wv * 256 + ct * 16 + c16) & 511;
            float r = bf2f(RB[row * 512 + j]);
            float z = bf2f(ZB[row * 512 + j]);
            float hn = bf2f(HB[row * 512 + j]);
            float h1v = bf2f(A1[row * 512 + (j ^ sw)]);
            float h2 = (1.f - z) * tanhf(acc[rt][ct][rr] + r * hn) + z * h1v;
            stnt(&yrow[j], h2);
            if (t == TT - 1) stnt(&out[(size_t)b * HH + j], h2);
          }
        }
    }
    __syncthreads();
  }
}

// ---------------- cleanup: cells with d >= RCAP (expected none) ----------------
__global__ __launch_bounds__(256, 1) void cleanup_kernel(
    const float* __restrict__ ins, const void* __restrict__ resets,
    const unsigned* __restrict__ cnt, const float* __restrict__ bi,
    const float* __restrict__ bh_n, const float* __restrict__ ln_s,
    const float* __restrict__ ln_b, const short* __restrict__ W0p,
    const short* __restrict__ W1p, float* __restrict__ out) {
  __shared__ float pre[2048];
  __shared__ float hbuf[512];
  __shared__ float red[4][4];
  const int b = blockIdx.x, tid = threadIdx.x;
  const int wv = tid >> 6, l = tid & 63;
  const int rmode = (int)cnt[FLAG_WORD];
  float* ys = out + BB * HH;
  int d = 0;
  for (int t = 0; t < TT; ++t) {
    bool rs = rmode ? (((const int*)resets)[t * BB + b] != 0)
                    : (((const unsigned char*)resets)[t * BB + b] != 0);
    d = (t == 0 || rs) ? 0 : d + 1;
    if (d < RCAP) continue;
    const float* hin = ys + (size_t)(t - 1) * (BB * HH) + (size_t)b * HH;
    const float* insr = ins + (size_t)t * (BB * HH) + (size_t)b * HH;
    for (int c = tid; c < 2048; c += 256) {
      float s = 0.f;
      for (int k = 0; k < 512; ++k) s += insr[k] * bf2f(W0p[w0idx(c, k)]);
      for (int k = 0; k < 512; ++k) s += hin[k] * bf2f(W0p[w0idx(c, 512 + k)]);
      pre[c] = s;
    }
    __syncthreads();
    float s0 = 0, q0 = 0, s1 = 0, q1 = 0;
    for (int j = tid; j < 512; j += 256) {
      float a = pre[j] + bi[j]; s0 += a; q0 += a * a;
      float c2 = pre[512 + j] + bi[512 + j]; s1 += c2; q1 += c2 * c2;
    }
#pragma unroll
    for (int o = 32; o >= 1; o >>= 1) {
      s0 += __shfl_xor(s0, o); q0 += __shfl_xor(q0, o);
      s1 += __shfl_xor(s1, o); q1 += __shfl_xor(q1, o);
    }
    if (l == 0) { red[wv][0] = s0; red[wv][1] = q0; red[wv][2] = s1; red[wv][3] = q1; }
    __syncthreads();
    float S0 = red[0][0] + red[1][0] + red[2][0] + red[3][0];
    float Q0 = red[0][1] + red[1][1] + red[2][1] + red[3][1];
    float S1 = red[0][2] + red[1][2] + red[2][2] + red[3][2];
    float Q1 = red[0][3] + red[1][3] + red[2][3] + red[3][3];
    float mr = S0 / 512.f, vr = Q0 / 512.f - mr * mr, ir = rsqrtf(vr + 1e-6f);
    float mz = S1 / 512.f, vz = Q1 / 512.f - mz * mz, iz = rsqrtf(vz + 1e-6f);
    __syncthreads();
    for (int j = tid; j < 512; j += 256) {
      float rg = sigf((pre[j] + bi[j] - mr) * ir * ln_s[j] + ln_b[j]);
      float zg = sigf((pre[512 + j] + bi[512 + j] - mz) * iz * ln_s[512 + j] + ln_b[512 + j]);
      float nn = tanhf(pre[1024 + j] + bi[1024 + j] + rg * (pre[1536 + j] + bh_n[j]));
      hbuf[j] = (1.f - zg) * nn + zg * hin[j];
    }
    __syncthreads();
    for (int c = tid; c < 2048; c += 256) {
      float s = 0.f;
      for (int k = 0; k < 512; ++k) s += hbuf[k] * bf2f(W1p[w1idx(c, k)]);
      pre[c] = s;
    }
    __syncthreads();
    s0 = 0; q0 = 0; s1 = 0; q1 = 0;
    for (int j = tid; j < 512; j += 256) {
      float a = pre[j] + bi[1536 + j]; s0 += a; q0 += a * a;
      float c2 = pre[512 + j] + bi[2048 + j]; s1 += c2; q1 += c2 * c2;
    }
#pragma unroll
    for (int o = 32; o >= 1; o >>= 1) {
      s0 += __shfl_xor(s0, o); q0 += __shfl_xor(q0, o);
      s1 += __shfl_xor(s1, o); q1 += __shfl_xor(q1, o);
    }
    if (l == 0) { red[wv][0] = s0; red[wv][1] = q0; red[wv][2] = s1; red[wv][3] = q1; }
    __syncthreads();
    S0 = red[0][0] + red[1][0] + red[2][0] + red[3][0];
    Q0 = red[0][1] + red[1][1] + red[2][1] + red[3][1];
    S1 = red[0][2] + red[1][2] + red[2][2] + red[3][2];
    Q1 = red[0][3] + red[1][3] + red[2][3] + red[3][3];
    mr = S0 / 512.f; vr = Q0 / 512.f - mr * mr; ir = rsqrtf(vr + 1e-6f);
    mz = S1 / 512.f; vz = Q1 / 512.f - mz * mz; iz = rsqrtf(vz + 1e-6f);
    __syncthreads();
    for (int j = tid; j < 512; j += 256) {
      float rg = sigf((pre[j] + bi[1536 + j] - mr) * ir * ln_s[1024 + j] + ln_b[1024 + j]);
      float zg = sigf((pre[512 + j] + bi[2048 + j] - mz) * iz * ln_s[1536 + j] + ln_b[1536 + j]);
      float nn = tanhf(pre[1024 + j] + bi[2560 + j] + rg * (pre[1536 + j] + bh_n[512 + j]));
      float h2 = (1.f - zg) * nn + zg * hbuf[j];
      ys[(size_t)t * (BB * HH) + (size_t)b * HH + j] = h2;
      if (t == TT - 1) out[(size_t)b * HH + j] = h2;
    }
    __syncthreads();
  }
}

extern "C" void kernel_launch(void* const* d_in, const int* in_sizes, int n_in,
                              void* d_out, int out_size, void* d_ws, size_t ws_size,
                              hipStream_t stream) {
  const float* ins   = (const float*)d_in[0];
  const void*  rstp  = d_in[1];
  const float* h0    = (const float*)d_in[2];
  const float* Wi    = (const float*)d_in[3];
  const float* bi    = (const float*)d_in[4];
  const float* Wh_rz = (const float*)d_in[5];
  const float* Wh_n  = (const float*)d_in[6];
  const float* bh_n  = (const float*)d_in[7];
  const float* ln_s  = (const float*)d_in[8];
  const float* ln_b  = (const float*)d_in[9];
  (void)in_sizes; (void)n_in; (void)out_size; (void)ws_size;

  char* ws = (char*)d_ws;
  unsigned* cnt = (unsigned*)ws;                       // off[0..RCAP] + flag @32768
  size_t off = 144 * 1024;
  u32*   bucket = (u32*)(ws + off);  off += (size_t)TT * BB * 4;       // 256 KB
  short* W0p    = (short*)(ws + off); off += (size_t)2048 * 1024 * 2;  // 4 MB
  short* W1p    = (short*)(ws + off); off += (size_t)2048 * 512 * 2;   // 2 MB

  (void)hipMemsetAsync(cnt, 0, (FLAG_WORD + 1) * sizeof(unsigned), stream);
  pack_kernel<<<1536, 256, 0, stream>>>(Wi, Wh_rz, Wh_n, rstp, W0p, W1p, cnt);
  prep_kernel<<<1, 128, 0, stream>>>(rstp, cnt, bucket);
  float* outp = (float*)d_out;
  for (int tau = 0; tau < RCAP; ++tau) {
    round_a<<<256, 512, 0, stream>>>(tau, ins, rstp, h0, bi, bh_n, ln_s, ln_b,
                                     W0p, cnt, bucket, outp);
    round_b<<<256, 512, 0, stream>>>(tau, bi, bh_n, ln_s, ln_b,
                                     W1p, cnt, bucket, outp);
  }
  cleanup_kernel<<<BB, 256, 0, stream>>>(ins, rstp, cnt, bi, bh_n, ln_s, ln_b,
                                         W0p, W1p, outp);
}

// Round 12
// 6258.419 us; speedup vs baseline: 1.9206x; 1.9206x over previous
//
#include <hip/hip_runtime.h>
#include <hip/hip_bf16.h>

// ScannedRNN: 2-cell LayerNorm-GRU scan. T=512, B=128, H=512.
// R12: working theory -- d_ws is fine-grained/uncached; streaming from it is
// latency-capped (~1 outstanding/wave). So: col-split G kernels stage their
// weight slice ws->LDS ONCE per dispatch; A comes from CACHED memory
// (ins=d_in, h=ys in d_out); pre goes through ws touched once each way.
// Bucketed rounds (cells at reset-distance tau), chunked for bounded ws use,
// procmap + sequential cleanup guarantees correctness for any resets.

#define TT 512
#define BB 128
#define HH 512
#define RCAP 20
#define CH 4096
#define FLAG_WORD 32768

typedef __attribute__((ext_vector_type(8))) short short8;
typedef __attribute__((ext_vector_type(4))) float f32x4;
typedef unsigned int u32;

__constant__ int D_NCH[RCAP] = {9,5,3,2,1,1,1,1,1,1,1,1,1,1,1,1,1,1,1,1};
static const int H_NCH[RCAP] = {9,5,3,2,1,1,1,1,1,1,1,1,1,1,1,1,1,1,1,1};

__device__ __forceinline__ short f2bf(float f) {
  unsigned u = __float_as_uint(f);
  unsigned r = (u + 0x7fffu + ((u >> 16) & 1u)) >> 16;
  return (short)r;
}
__device__ __forceinline__ float bf2f(short s) {
  return __uint_as_float(((unsigned)(unsigned short)s) << 16);
}
__device__ __forceinline__ float sigf(float x) { return 1.f / (1.f + __expf(-x)); }

// ---------------- pack: weights f32 -> bf16, PLAIN [col][k] layout ----------------
// W0p [2048][1024]: cols 0..511 r, 512..1023 z, 1024..1535 xn (ins half only,
// h half zero), 1536..2047 hn (h half only). k<512 = ins (Wi[0]), k>=512 = h.
// W1p [2048][512]: r,z = Wi1+Whrz1 folded; xn = Wi1_n; hn = Whn1.
__global__ void pack_kernel(const float* __restrict__ Wi, const float* __restrict__ Wh_rz,
                            const float* __restrict__ Wh_n, const void* __restrict__ resets,
                            short* __restrict__ W0p, short* __restrict__ W1p,
                            unsigned* __restrict__ cnt) {
  int gid = blockIdx.x * 256 + threadIdx.x;
  if (gid == 0) {
    const unsigned char* rb = (const unsigned char*)resets;
    unsigned intmode = 1u;
    for (int i = 1; i < 4096; ++i) {
      if ((i & 3) && rb[i]) { intmode = 0u; break; }
    }
    cnt[FLAG_WORD] = intmode;
  }
  const int n0 = 2048 * 128;
  const int n1 = 2048 * 64;
  if (gid < n0) {
    int col = gid & 2047, kb = (gid >> 11) * 8;
    int reg = col >> 9, j = col & 511;
    short8 o;
#pragma unroll
    for (int i = 0; i < 8; ++i) {
      int k = kb + i; float v;
      if (reg == 0)      v = (k < 512) ? Wi[(size_t)k * 1536 + j]        : Wh_rz[(size_t)(k - 512) * 1024 + j];
      else if (reg == 1) v = (k < 512) ? Wi[(size_t)k * 1536 + 512 + j]  : Wh_rz[(size_t)(k - 512) * 1024 + 512 + j];
      else if (reg == 2) v = (k < 512) ? Wi[(size_t)k * 1536 + 1024 + j] : 0.f;
      else               v = (k < 512) ? 0.f                             : Wh_n[(size_t)(k - 512) * 512 + j];
      o[i] = f2bf(v);
    }
    *(short8*)&W0p[(size_t)col * 1024 + kb] = o;
  } else if (gid < n0 + n1) {
    int g = gid - n0;
    int col = g & 2047, kb = (g >> 11) * 8;
    int reg = col >> 9, j = col & 511;
    const float* Wi1  = Wi + (size_t)512 * 1536;
    const float* Wrz1 = Wh_rz + (size_t)512 * 1024;
    const float* Wn1  = Wh_n + (size_t)512 * 512;
    short8 o;
#pragma unroll
    for (int i = 0; i < 8; ++i) {
      int k = kb + i; float v;
      if (reg == 0)      v = Wi1[(size_t)k * 1536 + j] + Wrz1[(size_t)k * 1024 + j];
      else if (reg == 1) v = Wi1[(size_t)k * 1536 + 512 + j] + Wrz1[(size_t)k * 1024 + 512 + j];
      else if (reg == 2) v = Wi1[(size_t)k * 1536 + 1024 + j];
      else               v = Wn1[(size_t)k * 512 + j];
      o[i] = f2bf(v);
    }
    *(short8*)&W1p[(size_t)col * 512 + kb] = o;
  }
}

// ---------------- prep: bucket cells by d, capped; procmap for fallback ----------------
__global__ void prep_kernel(const void* __restrict__ resets, unsigned* __restrict__ cnt,
                            u32* __restrict__ bucket, unsigned char* __restrict__ procmap) {
  __shared__ u32 cur[RCAP + 1];
  __shared__ int boff[RCAP];
  const int tid = threadIdx.x;
  const int rmode = (int)cnt[FLAG_WORD];
  const unsigned char* r8 = (const unsigned char*)resets;
  const int* r32 = (const int*)resets;
  if (tid <= RCAP) cur[tid] = 0;
  if (tid == 0) {
    int acc = 0;
    for (int i = 0; i < RCAP; ++i) { boff[i] = acc; acc += D_NCH[i] * CH; }
  }
  __syncthreads();
  if (tid < BB) {
    int d = 0;
    for (int t = 0; t < TT; ++t) {
      bool rs = rmode ? (r32[t * BB + tid] != 0) : (r8[t * BB + tid] != 0);
      d = (t == 0 || rs) ? 0 : d + 1;
      int dd = d < RCAP ? d : RCAP;
      u32 pos = atomicAdd(&cur[dd], 1u);
      bool ok = (dd < RCAP) && (pos < (u32)(D_NCH[dd] * CH));
      if (ok) bucket[boff[dd] + pos] = ((u32)t << 7) | (u32)tid;
      procmap[t * BB + tid] = ok ? 1 : 0;
    }
  }
  __syncthreads();
  if (tid < RCAP) {
    u32 cap = (u32)(D_NCH[tid] * CH);
    cnt[tid] = cur[tid] < cap ? cur[tid] : cap;
  }
}

// ---------------- g1: cell0 GEMM, col-split, W-slice in LDS ----------------
// grid 1024 = 32 colWGs x 32 group-lanes, 256 thr. 64 cols/WG, 16 rows/group.
__global__ __launch_bounds__(256, 1) void g1_kernel(
    int tau0, int chunkStart, const float* __restrict__ ins,
    const void* __restrict__ resets, const float* __restrict__ h0,
    const short* __restrict__ W0p, const unsigned* __restrict__ cnt, int tau,
    const u32* __restrict__ bucketSeg, float* __restrict__ pre,
    const float* __restrict__ ys) {
  __shared__ short lds[81920];      // 160 KB: W up to 64*1024, A 16*1024
  short* Wl = lds;
  short* A  = lds + 65536;
  const int tid = threadIdx.x;
  const u32 M = cnt[tau];
  if ((u32)chunkStart >= M) return;
  const u32 rem = M - (u32)chunkStart;
  const u32 chunkM = rem < (u32)CH ? rem : (u32)CH;
  const int cwg = blockIdx.x & 31;
  const int glane = blockIdx.x >> 5;
  if ((u32)(glane * 16) >= chunkM) return;
  const int col0 = cwg * 64;
  const int mode = (cwg < 16) ? 0 : ((cwg < 24) ? 1 : 2);  // 0=full,1=ins-half(xn),2=h-half(hn)
  const int KD = mode ? 512 : 1024;
  const int rmode = (int)cnt[FLAG_WORD];

  // stage W slice ws->LDS once (swizzled)
  const int nW = 64 * KD / 8;
  for (int i = tid; i < nW; i += 256) {
    int i8 = i * 8;
    int cl = i8 / KD, kk = i8 % KD;
    short8 v = *(const short8*)&W0p[(size_t)(col0 + cl) * 1024 + (mode == 2 ? 512 + kk : kk)];
    *(short8*)&Wl[cl * KD + (kk ^ ((cl & 7) << 3))] = v;
  }

  const int l = tid & 63, wv = tid >> 6, c16 = l & 15, kc = l >> 4;
  const int swl = (c16 & 7) << 3;

  for (u32 g = (u32)glane; g * 16 < chunkM; g += 32) {
    __syncthreads();
    // stage A: 16 rows x KD bf16 from cached sources
    const int nA = 16 * KD / 8;
    for (int i = tid; i < nA; i += 256) {
      int i8 = i * 8;
      int row = i8 / KD, kk = i8 % KD;
      u32 m = g * 16 + (u32)row;
      short8 v = {};
      if (m < chunkM) {
        u32 e = bucketSeg[chunkStart + m];
        int t = (int)((e >> 7) & 511), b = (int)(e & 127);
        int lk = (mode == 2) ? (512 + kk) : kk;   // logical k in [0,1024)
        const float* src = nullptr;
        if (lk < 512) {
          src = ins + (size_t)t * (BB * HH) + (size_t)b * HH + lk;
        } else {
          int hk = lk - 512;
          if (tau0) {
            bool rs = rmode ? (((const int*)resets)[t * BB + b] != 0)
                            : (((const unsigned char*)resets)[t * BB + b] != 0);
            src = rs ? nullptr : (h0 + (size_t)b * HH + hk);
          } else {
            src = ys + (size_t)(t - 1) * (BB * HH) + (size_t)b * HH + hk;
          }
        }
        if (src) {
          f32x4 u0 = *(const f32x4*)src;
          f32x4 u1 = *(const f32x4*)(src + 4);
          v[0] = f2bf(u0.x); v[1] = f2bf(u0.y); v[2] = f2bf(u0.z); v[3] = f2bf(u0.w);
          v[4] = f2bf(u1.x); v[5] = f2bf(u1.y); v[6] = f2bf(u1.z); v[7] = f2bf(u1.w);
        }
      }
      *(short8*)&A[row * KD + (kk ^ ((row & 7) << 3))] = v;
    }
    __syncthreads();
    // GEMM: wave wv -> cols [wv*16, wv*16+16)
    f32x4 acc = {0.f, 0.f, 0.f, 0.f};
    const int nkb = KD / 32;
    const int colL = wv * 16 + c16;
    for (int kb = 0; kb < nkb; ++kb) {
      int k = kb * 32 + kc * 8;
      short8 a   = *(const short8*)&A[c16 * KD + (k ^ swl)];
      short8 bfr = *(const short8*)&Wl[colL * KD + (k ^ swl)];
      acc = __builtin_amdgcn_mfma_f32_16x16x32_bf16(a, bfr, acc, 0, 0, 0);
    }
    const int colG = col0 + colL;
#pragma unroll
    for (int rr = 0; rr < 4; ++rr) {
      u32 m = g * 16 + (u32)(kc * 4 + rr);
      if (m < chunkM) pre[(size_t)m * 2048 + colG] = acc[rr];
    }
  }
}

// ---------------- g2: cell1 GEMM (K=512), col-split ----------------
// grid 1024 = 32 colWGs x 32 lanes, 256 thr. 64 cols/WG, 32 rows/group.
__global__ __launch_bounds__(256, 1) void g2_kernel(
    int chunkStart, const short* __restrict__ W1p, const unsigned* __restrict__ cnt,
    int tau, const u32* __restrict__ bucketSeg, float* __restrict__ pre,
    const float* __restrict__ ys) {
  __shared__ short lds[49152];      // 96 KB: W 64*512, A 32*512
  short* Wl = lds;
  short* A  = lds + 32768;
  const int tid = threadIdx.x;
  const u32 M = cnt[tau];
  if ((u32)chunkStart >= M) return;
  const u32 rem = M - (u32)chunkStart;
  const u32 chunkM = rem < (u32)CH ? rem : (u32)CH;
  const int cwg = blockIdx.x & 31;
  const int glane = blockIdx.x >> 5;
  if ((u32)(glane * 32) >= chunkM) return;
  const int col0 = cwg * 64;

  for (int i = tid; i < 64 * 512 / 8; i += 256) {
    int i8 = i * 8;
    int cl = i8 >> 9, kk = i8 & 511;
    short8 v = *(const short8*)&W1p[(size_t)(col0 + cl) * 512 + kk];
    *(short8*)&Wl[cl * 512 + (kk ^ ((cl & 7) << 3))] = v;
  }

  const int l = tid & 63, wv = tid >> 6, c16 = l & 15, kc = l >> 4;
  const int swl = (c16 & 7) << 3;

  for (u32 g = (u32)glane; g * 32 < chunkM; g += 32) {
    __syncthreads();
    // stage A: 32 rows x 512 (h1 from ys, cached)
    for (int i = tid; i < 32 * 512 / 8; i += 256) {
      int i8 = i * 8;
      int row = i8 >> 9, kk = i8 & 511;
      u32 m = g * 32 + (u32)row;
      short8 v = {};
      if (m < chunkM) {
        u32 e = bucketSeg[chunkStart + m];
        int t = (int)((e >> 7) & 511), b = (int)(e & 127);
        const float* src = ys + (size_t)t * (BB * HH) + (size_t)b * HH + kk;
        f32x4 u0 = *(const f32x4*)src;
        f32x4 u1 = *(const f32x4*)(src + 4);
        v[0] = f2bf(u0.x); v[1] = f2bf(u0.y); v[2] = f2bf(u0.z); v[3] = f2bf(u0.w);
        v[4] = f2bf(u1.x); v[5] = f2bf(u1.y); v[6] = f2bf(u1.z); v[7] = f2bf(u1.w);
      }
      *(short8*)&A[row * 512 + (kk ^ ((row & 7) << 3))] = v;
    }
    __syncthreads();
    // GEMM: wave wv -> cols [wv*16,..); rows 2 tiles
    f32x4 acc0 = {0.f,0.f,0.f,0.f}, acc1 = {0.f,0.f,0.f,0.f};
    const int colL = wv * 16 + c16;
    for (int kb = 0; kb < 16; ++kb) {
      int k = kb * 32 + kc * 8;
      short8 bfr = *(const short8*)&Wl[colL * 512 + (k ^ swl)];
      short8 a0  = *(const short8*)&A[c16 * 512 + (k ^ swl)];
      short8 a1  = *(const short8*)&A[(16 + c16) * 512 + (k ^ swl)];
      acc0 = __builtin_amdgcn_mfma_f32_16x16x32_bf16(a0, bfr, acc0, 0, 0, 0);
      acc1 = __builtin_amdgcn_mfma_f32_16x16x32_bf16(a1, bfr, acc1, 0, 0, 0);
    }
    const int colG = col0 + colL;
#pragma unroll
    for (int rr = 0; rr < 4; ++rr) {
      u32 m0 = g * 32 + (u32)(kc * 4 + rr);
      u32 m1 = m0 + 16;
      if (m0 < chunkM) pre[(size_t)m0 * 2048 + colG] = acc0[rr];
      if (m1 < chunkM) pre[(size_t)m1 * 2048 + colG] = acc1[rr];
    }
  }
}

// ---------------- ew0: LN+gates cell0 -> h1 (f32) into ys[t,b] ----------------
__global__ __launch_bounds__(256, 1) void ew0_kernel(
    int tau0, int chunkStart, const void* __restrict__ resets,
    const float* __restrict__ h0, const unsigned* __restrict__ cnt, int tau,
    const u32* __restrict__ bucketSeg, const float* __restrict__ pre,
    const float* __restrict__ bi, const float* __restrict__ bh_n,
    const float* __restrict__ ln_s, const float* __restrict__ ln_b,
    float* __restrict__ ys) {
  __shared__ float red[4][4];
  const int tid = threadIdx.x;
  const u32 M = cnt[tau];
  if ((u32)chunkStart >= M) return;
  const u32 rem = M - (u32)chunkStart;
  const u32 chunkM = rem < (u32)CH ? rem : (u32)CH;
  const int l = tid & 63, wv = tid >> 6;
  const int j0 = tid * 2;
  const int rmode = (int)cnt[FLAG_WORD];
  const float2 br = *(const float2*)&bi[j0];
  const float2 bz = *(const float2*)&bi[512 + j0];
  const float2 bn = *(const float2*)&bi[1024 + j0];
  const float2 bh = *(const float2*)&bh_n[j0];
  const float2 gsr = *(const float2*)&ln_s[j0],       gor = *(const float2*)&ln_b[j0];
  const float2 gsz = *(const float2*)&ln_s[512 + j0], goz = *(const float2*)&ln_b[512 + j0];

  for (u32 r = blockIdx.x; r < chunkM; r += 512) {
    __syncthreads();
    u32 e = bucketSeg[chunkStart + r];
    int t = (int)((e >> 7) & 511), b = (int)(e & 127);
    const float* prow = pre + (size_t)r * 2048;
    float2 pr = *(const float2*)&prow[j0];
    float2 pz = *(const float2*)&prow[512 + j0];
    float2 xn = *(const float2*)&prow[1024 + j0];
    float2 hn = *(const float2*)&prow[1536 + j0];
    pr.x += br.x; pr.y += br.y;
    pz.x += bz.x; pz.y += bz.y;
    float sr = pr.x + pr.y, sr2 = pr.x * pr.x + pr.y * pr.y;
    float sz = pz.x + pz.y, sz2 = pz.x * pz.x + pz.y * pz.y;
#pragma unroll
    for (int o = 32; o >= 1; o >>= 1) {
      sr += __shfl_xor(sr, o); sr2 += __shfl_xor(sr2, o);
      sz += __shfl_xor(sz, o); sz2 += __shfl_xor(sz2, o);
    }
    if (l == 0) { red[wv][0] = sr; red[wv][1] = sr2; red[wv][2] = sz; red[wv][3] = sz2; }
    __syncthreads();
    float Sr = red[0][0] + red[1][0] + red[2][0] + red[3][0];
    float Sr2 = red[0][1] + red[1][1] + red[2][1] + red[3][1];
    float Sz = red[0][2] + red[1][2] + red[2][2] + red[3][2];
    float Sz2 = red[0][3] + red[1][3] + red[2][3] + red[3][3];
    float mr = Sr * (1.f / 512.f), vr = Sr2 * (1.f / 512.f) - mr * mr;
    float mz = Sz * (1.f / 512.f), vz = Sz2 * (1.f / 512.f) - mz * mz;
    float ir = rsqrtf(vr + 1e-6f), iz = rsqrtf(vz + 1e-6f);
    float2 hp = {0.f, 0.f};
    if (tau0) {
      bool rs = rmode ? (((const int*)resets)[t * BB + b] != 0)
                      : (((const unsigned char*)resets)[t * BB + b] != 0);
      if (!rs) hp = *(const float2*)&h0[(size_t)b * HH + j0];
    } else {
      hp = *(const float2*)&ys[(size_t)(t - 1) * (BB * HH) + (size_t)b * HH + j0];
    }
    float2 h1;
    {
      float rg = sigf((pr.x - mr) * ir * gsr.x + gor.x);
      float zg = sigf((pz.x - mz) * iz * gsz.x + goz.x);
      float nn = tanhf(xn.x + bn.x + rg * (hn.x + bh.x));
      h1.x = (1.f - zg) * nn + zg * hp.x;
      rg = sigf((pr.y - mr) * ir * gsr.y + gor.y);
      zg = sigf((pz.y - mz) * iz * gsz.y + goz.y);
      nn = tanhf(xn.y + bn.y + rg * (hn.y + bh.y));
      h1.y = (1.f - zg) * nn + zg * hp.y;
    }
    *(float2*)&ys[(size_t)t * (BB * HH) + (size_t)b * HH + j0] = h1;
  }
}

// ---------------- ew1: LN+gates cell1 -> h2 into ys[t,b] (+out) ----------------
__global__ __launch_bounds__(256, 1) void ew1_kernel(
    int chunkStart, const unsigned* __restrict__ cnt, int tau,
    const u32* __restrict__ bucketSeg, const float* __restrict__ pre,
    const float* __restrict__ bi, const float* __restrict__ bh_n,
    const float* __restrict__ ln_s, const float* __restrict__ ln_b,
    float* __restrict__ ys, float* __restrict__ out) {
  __shared__ float red[4][4];
  const int tid = threadIdx.x;
  const u32 M = cnt[tau];
  if ((u32)chunkStart >= M) return;
  const u32 rem = M - (u32)chunkStart;
  const u32 chunkM = rem < (u32)CH ? rem : (u32)CH;
  const int l = tid & 63, wv = tid >> 6;
  const int j0 = tid * 2;
  const float2 br = *(const float2*)&bi[1536 + j0];
  const float2 bz = *(const float2*)&bi[2048 + j0];
  const float2 bn = *(const float2*)&bi[2560 + j0];
  const float2 bh = *(const float2*)&bh_n[512 + j0];
  const float2 gsr = *(const float2*)&ln_s[1024 + j0], gor = *(const float2*)&ln_b[1024 + j0];
  const float2 gsz = *(const float2*)&ln_s[1536 + j0], goz = *(const float2*)&ln_b[1536 + j0];

  for (u32 r = blockIdx.x; r < chunkM; r += 512) {
    __syncthreads();
    u32 e = bucketSeg[chunkStart + r];
    int t = (int)((e >> 7) & 511), b = (int)(e & 127);
    const float* prow = pre + (size_t)r * 2048;
    float2 pr = *(const float2*)&prow[j0];
    float2 pz = *(const float2*)&prow[512 + j0];
    float2 xn = *(const float2*)&prow[1024 + j0];
    float2 hn = *(const float2*)&prow[1536 + j0];
    pr.x += br.x; pr.y += br.y;
    pz.x += bz.x; pz.y += bz.y;
    float sr = pr.x + pr.y, sr2 = pr.x * pr.x + pr.y * pr.y;
    float sz = pz.x + pz.y, sz2 = pz.x * pz.x + pz.y * pz.y;
#pragma unroll
    for (int o = 32; o >= 1; o >>= 1) {
      sr += __shfl_xor(sr, o); sr2 += __shfl_xor(sr2, o);
      sz += __shfl_xor(sz, o); sz2 += __shfl_xor(sz2, o);
    }
    if (l == 0) { red[wv][0] = sr; red[wv][1] = sr2; red[wv][2] = sz; red[wv][3] = sz2; }
    __syncthreads();
    float Sr = red[0][0] + red[1][0] + red[2][0] + red[3][0];
    float Sr2 = red[0][1] + red[1][1] + red[2][1] + red[3][1];
    float Sz = red[0][2] + red[1][2] + red[2][2] + red[3][2];
    float Sz2 = red[0][3] + red[1][3] + red[2][3] + red[3][3];
    float mr = Sr * (1.f / 512.f), vr = Sr2 * (1.f / 512.f) - mr * mr;
    float mz = Sz * (1.f / 512.f), vz = Sz2 * (1.f / 512.f) - mz * mz;
    float ir = rsqrtf(vr + 1e-6f), iz = rsqrtf(vz + 1e-6f);
    float* yrow = ys + (size_t)t * (BB * HH) + (size_t)b * HH;
    float2 hp = *(const float2*)&yrow[j0];   // h1 (written by ew0)
    float2 h2;
    {
      float rg = sigf((pr.x - mr) * ir * gsr.x + gor.x);
      float zg = sigf((pz.x - mz) * iz * gsz.x + goz.x);
      float nn = tanhf(xn.x + bn.x + rg * (hn.x + bh.x));
      h2.x = (1.f - zg) * nn + zg * hp.x;
      rg = sigf((pr.y - mr) * ir * gsr.y + gor.y);
      zg = sigf((pz.y - mz) * iz * gsz.y + goz.y);
      nn = tanhf(xn.y + bn.y + rg * (hn.y + bh.y));
      h2.y = (1.f - zg) * nn + zg * hp.y;
    }
    *(float2*)&yrow[j0] = h2;
    if (t == TT - 1) *(float2*)&out[(size_t)b * HH + j0] = h2;
  }
}

// ---------------- cleanup: any cell with procmap==0 (sequential, expected none) ----------------
__global__ __launch_bounds__(256, 1) void cleanup_kernel(
    const float* __restrict__ ins, const void* __restrict__ resets,
    const unsigned* __restrict__ cnt, const unsigned char* __restrict__ procmap,
    const float* __restrict__ h0, const float* __restrict__ bi,
    const float* __restrict__ bh_n, const float* __restrict__ ln_s,
    const float* __restrict__ ln_b, const short* __restrict__ W0p,
    const short* __restrict__ W1p, float* __restrict__ out) {
  __shared__ float pre[2048];
  __shared__ float hbuf[512];
  __shared__ float red[4][4];
  const int b = blockIdx.x, tid = threadIdx.x;
  const int wv = tid >> 6, l = tid & 63;
  const int rmode = (int)cnt[FLAG_WORD];
  float* ys = out + BB * HH;
  for (int t = 0; t < TT; ++t) {
    if (procmap[t * BB + b]) continue;
    bool rs = rmode ? (((const int*)resets)[t * BB + b] != 0)
                    : (((const unsigned char*)resets)[t * BB + b] != 0);
    const float* hin = rs ? nullptr
                          : (t == 0 ? h0 + (size_t)b * HH
                                    : ys + (size_t)(t - 1) * (BB * HH) + (size_t)b * HH);
    const float* insr = ins + (size_t)t * (BB * HH) + (size_t)b * HH;
    for (int c = tid; c < 2048; c += 256) {
      float s = 0.f;
      const short* w = W0p + (size_t)c * 1024;
      for (int k = 0; k < 512; ++k) s += insr[k] * bf2f(w[k]);
      if (hin) for (int k = 0; k < 512; ++k) s += hin[k] * bf2f(w[512 + k]);
      pre[c] = s;
    }
    __syncthreads();
    float s0 = 0, q0 = 0, s1 = 0, q1 = 0;
    for (int j = tid; j < 512; j += 256) {
      float a = pre[j] + bi[j]; s0 += a; q0 += a * a;
      float c2 = pre[512 + j] + bi[512 + j]; s1 += c2; q1 += c2 * c2;
    }
#pragma unroll
    for (int o = 32; o >= 1; o >>= 1) {
      s0 += __shfl_xor(s0, o); q0 += __shfl_xor(q0, o);
      s1 += __shfl_xor(s1, o); q1 += __shfl_xor(q1, o);
    }
    if (l == 0) { red[wv][0] = s0; red[wv][1] = q0; red[wv][2] = s1; red[wv][3] = q1; }
    __syncthreads();
    float S0 = red[0][0] + red[1][0] + red[2][0] + red[3][0];
    float Q0 = red[0][1] + red[1][1] + red[2][1] + red[3][1];
    float S1 = red[0][2] + red[1][2] + red[2][2] + red[3][2];
    float Q1 = red[0][3] + red[1][3] + red[2][3] + red[3][3];
    float mr = S0 / 512.f, vr = Q0 / 512.f - mr * mr, ir = rsqrtf(vr + 1e-6f);
    float mz = S1 / 512.f, vz = Q1 / 512.f - mz * mz, iz = rsqrtf(vz + 1e-6f);
    __syncthreads();
    for (int j = tid; j < 512; j += 256) {
      float rg = sigf((pre[j] + bi[j] - mr) * ir * ln_s[j] + ln_b[j]);
      float zg = sigf((pre[512 + j] + bi[512 + j] - mz) * iz * ln_s[512 + j] + ln_b[512 + j]);
      float nn = tanhf(pre[1024 + j] + bi[1024 + j] + rg * (pre[1536 + j] + bh_n[j]));
      float hp = hin ? hin[j] : 0.f;
      hbuf[j] = (1.f - zg) * nn + zg * hp;
    }
    __syncthreads();
    for (int c = tid; c < 2048; c += 256) {
      float s = 0.f;
      const short* w = W1p + (size_t)c * 512;
      for (int k = 0; k < 512; ++k) s += hbuf[k] * bf2f(w[k]);
      pre[c] = s;
    }
    __syncthreads();
    s0 = 0; q0 = 0; s1 = 0; q1 = 0;
    for (int j = tid; j < 512; j += 256) {
      float a = pre[j] + bi[1536 + j]; s0 += a; q0 += a * a;
      float c2 = pre[512 + j] + bi[2048 + j]; s1 += c2; q1 += c2 * c2;
    }
#pragma unroll
    for (int o = 32; o >= 1; o >>= 1) {
      s0 += __shfl_xor(s0, o); q0 += __shfl_xor(q0, o);
      s1 += __shfl_xor(s1, o); q1 += __shfl_xor(q1, o);
    }
    if (l == 0) { red[wv][0] = s0; red[wv][1] = q0; red[wv][2] = s1; red[wv][3] = q1; }
    __syncthreads();
    S0 = red[0][0] + red[1][0] + red[2][0] + red[3][0];
    Q0 = red[0][1] + red[1][1] + red[2][1] + red[3][1];
    S1 = red[0][2] + red[1][2] + red[2][2] + red[3][2];
    Q1 = red[0][3] + red[1][3] + red[2][3] + red[3][3];
    mr = S0 / 512.f; vr = Q0 / 512.f - mr * mr; ir = rsqrtf(vr + 1e-6f);
    mz = S1 / 512.f; vz = Q1 / 512.f - mz * mz; iz = rsqrtf(vz + 1e-6f);
    __syncthreads();
    for (int j = tid; j < 512; j += 256) {
      float rg = sigf((pre[j] + bi[1536 + j] - mr) * ir * ln_s[1024 + j] + ln_b[1024 + j]);
      float zg = sigf((pre[512 + j] + bi[2048 + j] - mz) * iz * ln_s[1536 + j] + ln_b[1536 + j]);
      float nn = tanhf(pre[1024 + j] + bi[2560 + j] + rg * (pre[1536 + j] + bh_n[512 + j]));
      float h2 = (1.f - zg) * nn + zg * hbuf[j];
      ys[(size_t)t * (BB * HH) + (size_t)b * HH + j] = h2;
      if (t == TT - 1) out[(size_t)b * HH + j] = h2;
    }
    __syncthreads();
  }
}

extern "C" void kernel_launch(void* const* d_in, const int* in_sizes, int n_in,
                              void* d_out, int out_size, void* d_ws, size_t ws_size,
                              hipStream_t stream) {
  const float* ins   = (const float*)d_in[0];
  const void*  rstp  = d_in[1];
  const float* h0    = (const float*)d_in[2];
  const float* Wi    = (const float*)d_in[3];
  const float* bi    = (const float*)d_in[4];
  const float* Wh_rz = (const float*)d_in[5];
  const float* Wh_n  = (const float*)d_in[6];
  const float* bh_n  = (const float*)d_in[7];
  const float* ln_s  = (const float*)d_in[8];
  const float* ln_b  = (const float*)d_in[9];
  (void)in_sizes; (void)n_in; (void)out_size; (void)ws_size;

  char* ws = (char*)d_ws;
  unsigned* cnt = (unsigned*)ws;                        // cnt[0..RCAP) + flag @word 32768
  size_t off = 144 * 1024;
  unsigned char* procmap = (unsigned char*)(ws + off); off += 64 * 1024;
  u32*   bucket = (u32*)(ws + off);
  int totalCap = 0;
  for (int i = 0; i < RCAP; ++i) totalCap += H_NCH[i] * CH;
  off += (size_t)totalCap * 4;                          // ~573 KB
  off = (off + 255) & ~(size_t)255;
  short* W0p = (short*)(ws + off); off += (size_t)2048 * 1024 * 2;   // 4 MB
  short* W1p = (short*)(ws + off); off += (size_t)2048 * 512 * 2;    // 2 MB
  off = (off + 255) & ~(size_t)255;
  float* pre = (float*)(ws + off); off += (size_t)CH * 2048 * 4;     // 32 MB
  // total ws use ~40 MB

  (void)hipMemsetAsync(cnt, 0, (FLAG_WORD + 1) * sizeof(unsigned), stream);
  pack_kernel<<<1536, 256, 0, stream>>>(Wi, Wh_rz, Wh_n, rstp, W0p, W1p, cnt);
  prep_kernel<<<1, 128, 0, stream>>>(rstp, cnt, bucket, procmap);

  float* outp = (float*)d_out;
  float* ysp  = outp + BB * HH;
  int boff = 0;
  for (int tau = 0; tau < RCAP; ++tau) {
    const u32* seg = bucket + boff;
    const int tau0 = (tau == 0) ? 1 : 0;
    for (int c = 0; c < H_NCH[tau]; ++c) {
      int cs = c * CH;
      g1_kernel<<<1024, 256, 0, stream>>>(tau0, cs, ins, rstp, h0, W0p, cnt, tau,
                                          seg, pre, ysp);
      ew0_kernel<<<512, 256, 0, stream>>>(tau0, cs, rstp, h0, cnt, tau, seg, pre,
                                          bi, bh_n, ln_s, ln_b, ysp);
      g2_kernel<<<1024, 256, 0, stream>>>(cs, W1p, cnt, tau, seg, pre, ysp);
      ew1_kernel<<<512, 256, 0, stream>>>(cs, cnt, tau, seg, pre,
                                          bi, bh_n, ln_s, ln_b, ysp, outp);
    }
    boff += H_NCH[tau] * CH;
  }
  cleanup_kernel<<<BB, 256, 0, stream>>>(ins, rstp, cnt, procmap, h0, bi, bh_n,
                                         ln_s, ln_b, W0p, W1p, outp);
}

// Round 13
// 5710.328 us; speedup vs baseline: 2.1050x; 1.0960x over previous
//
#include <hip/hip_runtime.h>
#include <hip/hip_bf16.h>

// ScannedRNN: 2-cell LayerNorm-GRU scan. T=512, B=128, H=512.
// R13 = R12 + (a) parallel dtype-detect moved into prep (pack's serial
// 4096-byte scan was the single slowest kernel at ~306us), (b) W-stage
// redundancy halved: g1/g2 grids 32cwg x 16glane (was x32) -- each weight
// slice is staged from uncached ws 16x per dispatch instead of 32x.
// Theory: ws (d_ws) is fine-grained/uncached; all bulk ws traffic must be
// one-shot staged to LDS or touched once; A comes from cached d_in/d_out.

#define TT 512
#define BB 128
#define HH 512
#define RCAP 20
#define CH 4096
#define FLAG_WORD 32768

typedef __attribute__((ext_vector_type(8))) short short8;
typedef __attribute__((ext_vector_type(4))) float f32x4;
typedef unsigned int u32;

__constant__ int D_NCH[RCAP] = {9,5,3,2,1,1,1,1,1,1,1,1,1,1,1,1,1,1,1,1};
static const int H_NCH[RCAP] = {9,5,3,2,1,1,1,1,1,1,1,1,1,1,1,1,1,1,1,1};

__device__ __forceinline__ short f2bf(float f) {
  unsigned u = __float_as_uint(f);
  unsigned r = (u + 0x7fffu + ((u >> 16) & 1u)) >> 16;
  return (short)r;
}
__device__ __forceinline__ float bf2f(short s) {
  return __uint_as_float(((unsigned)(unsigned short)s) << 16);
}
__device__ __forceinline__ float sigf(float x) { return 1.f / (1.f + __expf(-x)); }

// ---------------- pack: weights f32 -> bf16, PLAIN [col][k] layout ----------------
__global__ void pack_kernel(const float* __restrict__ Wi, const float* __restrict__ Wh_rz,
                            const float* __restrict__ Wh_n,
                            short* __restrict__ W0p, short* __restrict__ W1p) {
  int gid = blockIdx.x * 256 + threadIdx.x;
  const int n0 = 2048 * 128;
  const int n1 = 2048 * 64;
  if (gid < n0) {
    int col = gid & 2047, kb = (gid >> 11) * 8;
    int reg = col >> 9, j = col & 511;
    short8 o;
#pragma unroll
    for (int i = 0; i < 8; ++i) {
      int k = kb + i; float v;
      if (reg == 0)      v = (k < 512) ? Wi[(size_t)k * 1536 + j]        : Wh_rz[(size_t)(k - 512) * 1024 + j];
      else if (reg == 1) v = (k < 512) ? Wi[(size_t)k * 1536 + 512 + j]  : Wh_rz[(size_t)(k - 512) * 1024 + 512 + j];
      else if (reg == 2) v = (k < 512) ? Wi[(size_t)k * 1536 + 1024 + j] : 0.f;
      else               v = (k < 512) ? 0.f                             : Wh_n[(size_t)(k - 512) * 512 + j];
      o[i] = f2bf(v);
    }
    *(short8*)&W0p[(size_t)col * 1024 + kb] = o;
  } else if (gid < n0 + n1) {
    int g = gid - n0;
    int col = g & 2047, kb = (g >> 11) * 8;
    int reg = col >> 9, j = col & 511;
    const float* Wi1  = Wi + (size_t)512 * 1536;
    const float* Wrz1 = Wh_rz + (size_t)512 * 1024;
    const float* Wn1  = Wh_n + (size_t)512 * 512;
    short8 o;
#pragma unroll
    for (int i = 0; i < 8; ++i) {
      int k = kb + i; float v;
      if (reg == 0)      v = Wi1[(size_t)k * 1536 + j] + Wrz1[(size_t)k * 1024 + j];
      else if (reg == 1) v = Wi1[(size_t)k * 1536 + 512 + j] + Wrz1[(size_t)k * 1024 + 512 + j];
      else if (reg == 2) v = Wi1[(size_t)k * 1536 + 1024 + j];
      else               v = Wn1[(size_t)k * 512 + j];
      o[i] = f2bf(v);
    }
    *(short8*)&W1p[(size_t)col * 512 + kb] = o;
  }
}

// ---------------- prep: parallel dtype-detect + bucket cells by d ----------------
__global__ void prep_kernel(const void* __restrict__ resets, unsigned* __restrict__ cnt,
                            u32* __restrict__ bucket, unsigned char* __restrict__ procmap) {
  __shared__ u32 cur[RCAP + 1];
  __shared__ int boff[RCAP];
  __shared__ unsigned nzOdd;
  const int tid = threadIdx.x;
  const unsigned char* r8 = (const unsigned char*)resets;
  const int* r32 = (const int*)resets;
  if (tid == 0) nzOdd = 0;
  if (tid <= RCAP) cur[tid] = 0;
  if (tid == 0) {
    int acc = 0;
    for (int i = 0; i < RCAP; ++i) { boff[i] = acc; acc += D_NCH[i] * CH; }
  }
  __syncthreads();
  // parallel dtype detect: int32 mode iff bytes at i%4!=0 are all zero in first 4KB
  {
    const u32* w = (const u32*)resets;
    u32 acc = 0;
    for (int i = tid * 8; i < tid * 8 + 8; ++i) acc |= w[i] & 0xFFFFFF00u;
    if (acc) atomicOr(&nzOdd, 1u);
  }
  __syncthreads();
  const int rmode = nzOdd ? 0 : 1;
  if (tid == 0) cnt[FLAG_WORD] = (unsigned)rmode;
  if (tid < BB) {
    int d = 0;
    for (int t = 0; t < TT; ++t) {
      bool rs = rmode ? (r32[t * BB + tid] != 0) : (r8[t * BB + tid] != 0);
      d = (t == 0 || rs) ? 0 : d + 1;
      int dd = d < RCAP ? d : RCAP;
      u32 pos = atomicAdd(&cur[dd], 1u);
      bool ok = (dd < RCAP) && (pos < (u32)(D_NCH[dd] * CH));
      if (ok) bucket[boff[dd] + pos] = ((u32)t << 7) | (u32)tid;
      procmap[t * BB + tid] = ok ? 1 : 0;
    }
  }
  __syncthreads();
  if (tid < RCAP) {
    u32 cap = (u32)(D_NCH[tid] * CH);
    cnt[tid] = cur[tid] < cap ? cur[tid] : cap;
  }
}

// ---------------- g1: cell0 GEMM, col-split, W-slice in LDS ----------------
// grid 512 = 32 colWGs x 16 group-lanes, 256 thr. 64 cols/WG, 16 rows/group.
__global__ __launch_bounds__(256, 1) void g1_kernel(
    int tau0, int chunkStart, const float* __restrict__ ins,
    const void* __restrict__ resets, const float* __restrict__ h0,
    const short* __restrict__ W0p, const unsigned* __restrict__ cnt, int tau,
    const u32* __restrict__ bucketSeg, float* __restrict__ pre,
    const float* __restrict__ ys) {
  __shared__ short lds[81920];      // 160 KB: W up to 64*1024, A 16*1024
  short* Wl = lds;
  short* A  = lds + 65536;
  const int tid = threadIdx.x;
  const u32 M = cnt[tau];
  if ((u32)chunkStart >= M) return;
  const u32 rem = M - (u32)chunkStart;
  const u32 chunkM = rem < (u32)CH ? rem : (u32)CH;
  const int cwg = blockIdx.x & 31;
  const int glane = blockIdx.x >> 5;       // 0..15
  if ((u32)(glane * 16) >= chunkM) return;
  const int col0 = cwg * 64;
  const int mode = (cwg < 16) ? 0 : ((cwg < 24) ? 1 : 2);  // 0=full,1=ins-half(xn),2=h-half(hn)
  const int KD = mode ? 512 : 1024;
  const int rmode = (int)cnt[FLAG_WORD];

  // stage W slice ws->LDS once (swizzled)
  const int nW = 64 * KD / 8;
  for (int i = tid; i < nW; i += 256) {
    int i8 = i * 8;
    int cl = i8 / KD, kk = i8 % KD;
    short8 v = *(const short8*)&W0p[(size_t)(col0 + cl) * 1024 + (mode == 2 ? 512 + kk : kk)];
    *(short8*)&Wl[cl * KD + (kk ^ ((cl & 7) << 3))] = v;
  }

  const int l = tid & 63, wv = tid >> 6, c16 = l & 15, kc = l >> 4;
  const int swl = (c16 & 7) << 3;

  for (u32 g = (u32)glane; g * 16 < chunkM; g += 16) {
    __syncthreads();
    // stage A: 16 rows x KD bf16 from cached sources
    const int nA = 16 * KD / 8;
    for (int i = tid; i < nA; i += 256) {
      int i8 = i * 8;
      int row = i8 / KD, kk = i8 % KD;
      u32 m = g * 16 + (u32)row;
      short8 v = {};
      if (m < chunkM) {
        u32 e = bucketSeg[chunkStart + m];
        int t = (int)((e >> 7) & 511), b = (int)(e & 127);
        int lk = (mode == 2) ? (512 + kk) : kk;   // logical k in [0,1024)
        const float* src = nullptr;
        if (lk < 512) {
          src = ins + (size_t)t * (BB * HH) + (size_t)b * HH + lk;
        } else {
          int hk = lk - 512;
          if (tau0) {
            bool rs = rmode ? (((const int*)resets)[t * BB + b] != 0)
                            : (((const unsigned char*)resets)[t * BB + b] != 0);
            src = rs ? nullptr : (h0 + (size_t)b * HH + hk);
          } else {
            src = ys + (size_t)(t - 1) * (BB * HH) + (size_t)b * HH + hk;
          }
        }
        if (src) {
          f32x4 u0 = *(const f32x4*)src;
          f32x4 u1 = *(const f32x4*)(src + 4);
          v[0] = f2bf(u0.x); v[1] = f2bf(u0.y); v[2] = f2bf(u0.z); v[3] = f2bf(u0.w);
          v[4] = f2bf(u1.x); v[5] = f2bf(u1.y); v[6] = f2bf(u1.z); v[7] = f2bf(u1.w);
        }
      }
      *(short8*)&A[row * KD + (kk ^ ((row & 7) << 3))] = v;
    }
    __syncthreads();
    // GEMM: wave wv -> cols [wv*16, wv*16+16)
    f32x4 acc = {0.f, 0.f, 0.f, 0.f};
    const int nkb = KD / 32;
    const int colL = wv * 16 + c16;
    for (int kb = 0; kb < nkb; ++kb) {
      int k = kb * 32 + kc * 8;
      short8 a   = *(const short8*)&A[c16 * KD + (k ^ swl)];
      short8 bfr = *(const short8*)&Wl[colL * KD + (k ^ swl)];
      acc = __builtin_amdgcn_mfma_f32_16x16x32_bf16(a, bfr, acc, 0, 0, 0);
    }
    const int colG = col0 + colL;
#pragma unroll
    for (int rr = 0; rr < 4; ++rr) {
      u32 m = g * 16 + (u32)(kc * 4 + rr);
      if (m < chunkM) pre[(size_t)m * 2048 + colG] = acc[rr];
    }
  }
}

// ---------------- g2: cell1 GEMM (K=512), col-split ----------------
// grid 512 = 32 colWGs x 16 lanes, 256 thr. 64 cols/WG, 32 rows/group.
__global__ __launch_bounds__(256, 1) void g2_kernel(
    int chunkStart, const short* __restrict__ W1p, const unsigned* __restrict__ cnt,
    int tau, const u32* __restrict__ bucketSeg, float* __restrict__ pre,
    const float* __restrict__ ys) {
  __shared__ short lds[49152];      // 96 KB: W 64*512, A 32*512
  short* Wl = lds;
  short* A  = lds + 32768;
  const int tid = threadIdx.x;
  const u32 M = cnt[tau];
  if ((u32)chunkStart >= M) return;
  const u32 rem = M - (u32)chunkStart;
  const u32 chunkM = rem < (u32)CH ? rem : (u32)CH;
  const int cwg = blockIdx.x & 31;
  const int glane = blockIdx.x >> 5;       // 0..15
  if ((u32)(glane * 32) >= chunkM) return;
  const int col0 = cwg * 64;

  for (int i = tid; i < 64 * 512 / 8; i += 256) {
    int i8 = i * 8;
    int cl = i8 >> 9, kk = i8 & 511;
    short8 v = *(const short8*)&W1p[(size_t)(col0 + cl) * 512 + kk];
    *(short8*)&Wl[cl * 512 + (kk ^ ((cl & 7) << 3))] = v;
  }

  const int l = tid & 63, wv = tid >> 6, c16 = l & 15, kc = l >> 4;
  const int swl = (c16 & 7) << 3;

  for (u32 g = (u32)glane; g * 32 < chunkM; g += 16) {
    __syncthreads();
    // stage A: 32 rows x 512 (h1 from ys, cached)
    for (int i = tid; i < 32 * 512 / 8; i += 256) {
      int i8 = i * 8;
      int row = i8 >> 9, kk = i8 & 511;
      u32 m = g * 32 + (u32)row;
      short8 v = {};
      if (m < chunkM) {
        u32 e = bucketSeg[chunkStart + m];
        int t = (int)((e >> 7) & 511), b = (int)(e & 127);
        const float* src = ys + (size_t)t * (BB * HH) + (size_t)b * HH + kk;
        f32x4 u0 = *(const f32x4*)src;
        f32x4 u1 = *(const f32x4*)(src + 4);
        v[0] = f2bf(u0.x); v[1] = f2bf(u0.y); v[2] = f2bf(u0.z); v[3] = f2bf(u0.w);
        v[4] = f2bf(u1.x); v[5] = f2bf(u1.y); v[6] = f2bf(u1.z); v[7] = f2bf(u1.w);
      }
      *(short8*)&A[row * 512 + (kk ^ ((row & 7) << 3))] = v;
    }
    __syncthreads();
    f32x4 acc0 = {0.f,0.f,0.f,0.f}, acc1 = {0.f,0.f,0.f,0.f};
    const int colL = wv * 16 + c16;
    for (int kb = 0; kb < 16; ++kb) {
      int k = kb * 32 + kc * 8;
      short8 bfr = *(const short8*)&Wl[colL * 512 + (k ^ swl)];
      short8 a0  = *(const short8*)&A[c16 * 512 + (k ^ swl)];
      short8 a1  = *(const short8*)&A[(16 + c16) * 512 + (k ^ swl)];
      acc0 = __builtin_amdgcn_mfma_f32_16x16x32_bf16(a0, bfr, acc0, 0, 0, 0);
      acc1 = __builtin_amdgcn_mfma_f32_16x16x32_bf16(a1, bfr, acc1, 0, 0, 0);
    }
    const int colG = col0 + colL;
#pragma unroll
    for (int rr = 0; rr < 4; ++rr) {
      u32 m0 = g * 32 + (u32)(kc * 4 + rr);
      u32 m1 = m0 + 16;
      if (m0 < chunkM) pre[(size_t)m0 * 2048 + colG] = acc0[rr];
      if (m1 < chunkM) pre[(size_t)m1 * 2048 + colG] = acc1[rr];
    }
  }
}

// ---------------- ew0: LN+gates cell0 -> h1 (f32) into ys[t,b] ----------------
__global__ __launch_bounds__(256, 1) void ew0_kernel(
    int tau0, int chunkStart, const void* __restrict__ resets,
    const float* __restrict__ h0, const unsigned* __restrict__ cnt, int tau,
    const u32* __restrict__ bucketSeg, const float* __restrict__ pre,
    const float* __restrict__ bi, const float* __restrict__ bh_n,
    const float* __restrict__ ln_s, const float* __restrict__ ln_b,
    float* __restrict__ ys) {
  __shared__ float red[4][4];
  const int tid = threadIdx.x;
  const u32 M = cnt[tau];
  if ((u32)chunkStart >= M) return;
  const u32 rem = M - (u32)chunkStart;
  const u32 chunkM = rem < (u32)CH ? rem : (u32)CH;
  const int l = tid & 63, wv = tid >> 6;
  const int j0 = tid * 2;
  const int rmode = (int)cnt[FLAG_WORD];
  const float2 br = *(const float2*)&bi[j0];
  const float2 bz = *(const float2*)&bi[512 + j0];
  const float2 bn = *(const float2*)&bi[1024 + j0];
  const float2 bh = *(const float2*)&bh_n[j0];
  const float2 gsr = *(const float2*)&ln_s[j0],       gor = *(const float2*)&ln_b[j0];
  const float2 gsz = *(const float2*)&ln_s[512 + j0], goz = *(const float2*)&ln_b[512 + j0];

  for (u32 r = blockIdx.x; r < chunkM; r += 512) {
    __syncthreads();
    u32 e = bucketSeg[chunkStart + r];
    int t = (int)((e >> 7) & 511), b = (int)(e & 127);
    const float* prow = pre + (size_t)r * 2048;
    float2 pr = *(const float2*)&prow[j0];
    float2 pz = *(const float2*)&prow[512 + j0];
    float2 xn = *(const float2*)&prow[1024 + j0];
    float2 hn = *(const float2*)&prow[1536 + j0];
    pr.x += br.x; pr.y += br.y;
    pz.x += bz.x; pz.y += bz.y;
    float sr = pr.x + pr.y, sr2 = pr.x * pr.x + pr.y * pr.y;
    float sz = pz.x + pz.y, sz2 = pz.x * pz.x + pz.y * pz.y;
#pragma unroll
    for (int o = 32; o >= 1; o >>= 1) {
      sr += __shfl_xor(sr, o); sr2 += __shfl_xor(sr2, o);
      sz += __shfl_xor(sz, o); sz2 += __shfl_xor(sz2, o);
    }
    if (l == 0) { red[wv][0] = sr; red[wv][1] = sr2; red[wv][2] = sz; red[wv][3] = sz2; }
    __syncthreads();
    float Sr = red[0][0] + red[1][0] + red[2][0] + red[3][0];
    float Sr2 = red[0][1] + red[1][1] + red[2][1] + red[3][1];
    float Sz = red[0][2] + red[1][2] + red[2][2] + red[3][2];
    float Sz2 = red[0][3] + red[1][3] + red[2][3] + red[3][3];
    float mr = Sr * (1.f / 512.f), vr = Sr2 * (1.f / 512.f) - mr * mr;
    float mz = Sz * (1.f / 512.f), vz = Sz2 * (1.f / 512.f) - mz * mz;
    float ir = rsqrtf(vr + 1e-6f), iz = rsqrtf(vz + 1e-6f);
    float2 hp = {0.f, 0.f};
    if (tau0) {
      bool rs = rmode ? (((const int*)resets)[t * BB + b] != 0)
                      : (((const unsigned char*)resets)[t * BB + b] != 0);
      if (!rs) hp = *(const float2*)&h0[(size_t)b * HH + j0];
    } else {
      hp = *(const float2*)&ys[(size_t)(t - 1) * (BB * HH) + (size_t)b * HH + j0];
    }
    float2 h1;
    {
      float rg = sigf((pr.x - mr) * ir * gsr.x + gor.x);
      float zg = sigf((pz.x - mz) * iz * gsz.x + goz.x);
      float nn = tanhf(xn.x + bn.x + rg * (hn.x + bh.x));
      h1.x = (1.f - zg) * nn + zg * hp.x;
      rg = sigf((pr.y - mr) * ir * gsr.y + gor.y);
      zg = sigf((pz.y - mz) * iz * gsz.y + goz.y);
      nn = tanhf(xn.y + bn.y + rg * (hn.y + bh.y));
      h1.y = (1.f - zg) * nn + zg * hp.y;
    }
    *(float2*)&ys[(size_t)t * (BB * HH) + (size_t)b * HH + j0] = h1;
  }
}

// ---------------- ew1: LN+gates cell1 -> h2 into ys[t,b] (+out) ----------------
__global__ __launch_bounds__(256, 1) void ew1_kernel(
    int chunkStart, const unsigned* __restrict__ cnt, int tau,
    const u32* __restrict__ bucketSeg, const float* __restrict__ pre,
    const float* __restrict__ bi, const float* __restrict__ bh_n,
    const float* __restrict__ ln_s, const float* __restrict__ ln_b,
    float* __restrict__ ys, float* __restrict__ out) {
  __shared__ float red[4][4];
  const int tid = threadIdx.x;
  const u32 M = cnt[tau];
  if ((u32)chunkStart >= M) return;
  const u32 rem = M - (u32)chunkStart;
  const u32 chunkM = rem < (u32)CH ? rem : (u32)CH;
  const int l = tid & 63, wv = tid >> 6;
  const int j0 = tid * 2;
  const float2 br = *(const float2*)&bi[1536 + j0];
  const float2 bz = *(const float2*)&bi[2048 + j0];
  const float2 bn = *(const float2*)&bi[2560 + j0];
  const float2 bh = *(const float2*)&bh_n[512 + j0];
  const float2 gsr = *(const float2*)&ln_s[1024 + j0], gor = *(const float2*)&ln_b[1024 + j0];
  const float2 gsz = *(const float2*)&ln_s[1536 + j0], goz = *(const float2*)&ln_b[1536 + j0];

  for (u32 r = blockIdx.x; r < chunkM; r += 512) {
    __syncthreads();
    u32 e = bucketSeg[chunkStart + r];
    int t = (int)((e >> 7) & 511), b = (int)(e & 127);
    const float* prow = pre + (size_t)r * 2048;
    float2 pr = *(const float2*)&prow[j0];
    float2 pz = *(const float2*)&prow[512 + j0];
    float2 xn = *(const float2*)&prow[1024 + j0];
    float2 hn = *(const float2*)&prow[1536 + j0];
    pr.x += br.x; pr.y += br.y;
    pz.x += bz.x; pz.y += bz.y;
    float sr = pr.x + pr.y, sr2 = pr.x * pr.x + pr.y * pr.y;
    float sz = pz.x + pz.y, sz2 = pz.x * pz.x + pz.y * pz.y;
#pragma unroll
    for (int o = 32; o >= 1; o >>= 1) {
      sr += __shfl_xor(sr, o); sr2 += __shfl_xor(sr2, o);
      sz += __shfl_xor(sz, o); sz2 += __shfl_xor(sz2, o);
    }
    if (l == 0) { red[wv][0] = sr; red[wv][1] = sr2; red[wv][2] = sz; red[wv][3] = sz2; }
    __syncthreads();
    float Sr = red[0][0] + red[1][0] + red[2][0] + red[3][0];
    float Sr2 = red[0][1] + red[1][1] + red[2][1] + red[3][1];
    float Sz = red[0][2] + red[1][2] + red[2][2] + red[3][2];
    float Sz2 = red[0][3] + red[1][3] + red[2][3] + red[3][3];
    float mr = Sr * (1.f / 512.f), vr = Sr2 * (1.f / 512.f) - mr * mr;
    float mz = Sz * (1.f / 512.f), vz = Sz2 * (1.f / 512.f) - mz * mz;
    float ir = rsqrtf(vr + 1e-6f), iz = rsqrtf(vz + 1e-6f);
    float* yrow = ys + (size_t)t * (BB * HH) + (size_t)b * HH;
    float2 hp = *(const float2*)&yrow[j0];   // h1 (written by ew0)
    float2 h2;
    {
      float rg = sigf((pr.x - mr) * ir * gsr.x + gor.x);
      float zg = sigf((pz.x - mz) * iz * gsz.x + goz.x);
      float nn = tanhf(xn.x + bn.x + rg * (hn.x + bh.x));
      h2.x = (1.f - zg) * nn + zg * hp.x;
      rg = sigf((pr.y - mr) * ir * gsr.y + gor.y);
      zg = sigf((pz.y - mz) * iz * gsz.y + goz.y);
      nn = tanhf(xn.y + bn.y + rg * (hn.y + bh.y));
      h2.y = (1.f - zg) * nn + zg * hp.y;
    }
    *(float2*)&yrow[j0] = h2;
    if (t == TT - 1) *(float2*)&out[(size_t)b * HH + j0] = h2;
  }
}

// ---------------- cleanup: any cell with procmap==0 (sequential, expected none) ----------------
__global__ __launch_bounds__(256, 1) void cleanup_kernel(
    const float* __restrict__ ins, const void* __restrict__ resets,
    const unsigned* __restrict__ cnt, const unsigned char* __restrict__ procmap,
    const float* __restrict__ h0, const float* __restrict__ bi,
    const float* __restrict__ bh_n, const float* __restrict__ ln_s,
    const float* __restrict__ ln_b, const short* __restrict__ W0p,
    const short* __restrict__ W1p, float* __restrict__ out) {
  __shared__ float pre[2048];
  __shared__ float hbuf[512];
  __shared__ float red[4][4];
  const int b = blockIdx.x, tid = threadIdx.x;
  const int wv = tid >> 6, l = tid & 63;
  const int rmode = (int)cnt[FLAG_WORD];
  float* ys = out + BB * HH;
  for (int t = 0; t < TT; ++t) {
    if (procmap[t * BB + b]) continue;
    bool rs = rmode ? (((const int*)resets)[t * BB + b] != 0)
                    : (((const unsigned char*)resets)[t * BB + b] != 0);
    const float* hin = rs ? nullptr
                          : (t == 0 ? h0 + (size_t)b * HH
                                    : ys + (size_t)(t - 1) * (BB * HH) + (size_t)b * HH);
    const float* insr = ins + (size_t)t * (BB * HH) + (size_t)b * HH;
    for (int c = tid; c < 2048; c += 256) {
      float s = 0.f;
      const short* w = W0p + (size_t)c * 1024;
      for (int k = 0; k < 512; ++k) s += insr[k] * bf2f(w[k]);
      if (hin) for (int k = 0; k < 512; ++k) s += hin[k] * bf2f(w[512 + k]);
      pre[c] = s;
    }
    __syncthreads();
    float s0 = 0, q0 = 0, s1 = 0, q1 = 0;
    for (int j = tid; j < 512; j += 256) {
      float a = pre[j] + bi[j]; s0 += a; q0 += a * a;
      float c2 = pre[512 + j] + bi[512 + j]; s1 += c2; q1 += c2 * c2;
    }
#pragma unroll
    for (int o = 32; o >= 1; o >>= 1) {
      s0 += __shfl_xor(s0, o); q0 += __shfl_xor(q0, o);
      s1 += __shfl_xor(s1, o); q1 += __shfl_xor(q1, o);
    }
    if (l == 0) { red[wv][0] = s0; red[wv][1] = q0; red[wv][2] = s1; red[wv][3] = q1; }
    __syncthreads();
    float S0 = red[0][0] + red[1][0] + red[2][0] + red[3][0];
    float Q0 = red[0][1] + red[1][1] + red[2][1] + red[3][1];
    float S1 = red[0][2] + red[1][2] + red[2][2] + red[3][2];
    float Q1 = red[0][3] + red[1][3] + red[2][3] + red[3][3];
    float mr = S0 / 512.f, vr = Q0 / 512.f - mr * mr, ir = rsqrtf(vr + 1e-6f);
    float mz = S1 / 512.f, vz = Q1 / 512.f - mz * mz, iz = rsqrtf(vz + 1e-6f);
    __syncthreads();
    for (int j = tid; j < 512; j += 256) {
      float rg = sigf((pre[j] + bi[j] - mr) * ir * ln_s[j] + ln_b[j]);
      float zg = sigf((pre[512 + j] + bi[512 + j] - mz) * iz * ln_s[512 + j] + ln_b[512 + j]);
      float nn = tanhf(pre[1024 + j] + bi[1024 + j] + rg * (pre[1536 + j] + bh_n[j]));
      float hp = hin ? hin[j] : 0.f;
      hbuf[j] = (1.f - zg) * nn + zg * hp;
    }
    __syncthreads();
    for (int c = tid; c < 2048; c += 256) {
      float s = 0.f;
      const short* w = W1p + (size_t)c * 512;
      for (int k = 0; k < 512; ++k) s += hbuf[k] * bf2f(w[k]);
      pre[c] = s;
    }
    __syncthreads();
    s0 = 0; q0 = 0; s1 = 0; q1 = 0;
    for (int j = tid; j < 512; j += 256) {
      float a = pre[j] + bi[1536 + j]; s0 += a; q0 += a * a;
      float c2 = pre[512 + j] + bi[2048 + j]; s1 += c2; q1 += c2 * c2;
    }
#pragma unroll
    for (int o = 32; o >= 1; o >>= 1) {
      s0 += __shfl_xor(s0, o); q0 += __shfl_xor(q0, o);
      s1 += __shfl_xor(s1, o); q1 += __shfl_xor(q1, o);
    }
    if (l == 0) { red[wv][0] = s0; red[wv][1] = q0; red[wv][2] = s1; red[wv][3] = q1; }
    __syncthreads();
    S0 = red[0][0] + red[1][0] + red[2][0] + red[3][0];
    Q0 = red[0][1] + red[1][1] + red[2][1] + red[3][1];
    S1 = red[0][2] + red[1][2] + red[2][2] + red[3][2];
    Q1 = red[0][3] + red[1][3] + red[2][3] + red[3][3];
    mr = S0 / 512.f; vr = Q0 / 512.f - mr * mr; ir = rsqrtf(vr + 1e-6f);
    mz = S1 / 512.f; vz = Q1 / 512.f - mz * mz; iz = rsqrtf(vz + 1e-6f);
    __syncthreads();
    for (int j = tid; j < 512; j += 256) {
      float rg = sigf((pre[j] + bi[1536 + j] - mr) * ir * ln_s[1024 + j] + ln_b[1024 + j]);
      float zg = sigf((pre[512 + j] + bi[2048 + j] - mz) * iz * ln_s[1536 + j] + ln_b[1536 + j]);
      float nn = tanhf(pre[1024 + j] + bi[2560 + j] + rg * (pre[1536 + j] + bh_n[512 + j]));
      float h2 = (1.f - zg) * nn + zg * hbuf[j];
      ys[(size_t)t * (BB * HH) + (size_t)b * HH + j] = h2;
      if (t == TT - 1) out[(size_t)b * HH + j] = h2;
    }
    __syncthreads();
  }
}

extern "C" void kernel_launch(void* const* d_in, const int* in_sizes, int n_in,
                              void* d_out, int out_size, void* d_ws, size_t ws_size,
                              hipStream_t stream) {
  const float* ins   = (const float*)d_in[0];
  const void*  rstp  = d_in[1];
  const float* h0    = (const float*)d_in[2];
  const float* Wi    = (const float*)d_in[3];
  const float* bi    = (const float*)d_in[4];
  const float* Wh_rz = (const float*)d_in[5];
  const float* Wh_n  = (const float*)d_in[6];
  const float* bh_n  = (const float*)d_in[7];
  const float* ln_s  = (const float*)d_in[8];
  const float* ln_b  = (const float*)d_in[9];
  (void)in_sizes; (void)n_in; (void)out_size; (void)ws_size;

  char* ws = (char*)d_ws;
  unsigned* cnt = (unsigned*)ws;                        // cnt[0..RCAP) + flag @word 32768
  size_t off = 144 * 1024;
  unsigned char* procmap = (unsigned char*)(ws + off); off += 64 * 1024;
  u32*   bucket = (u32*)(ws + off);
  int totalCap = 0;
  for (int i = 0; i < RCAP; ++i) totalCap += H_NCH[i] * CH;
  off += (size_t)totalCap * 4;
  off = (off + 255) & ~(size_t)255;
  short* W0p = (short*)(ws + off); off += (size_t)2048 * 1024 * 2;   // 4 MB
  short* W1p = (short*)(ws + off); off += (size_t)2048 * 512 * 2;    // 2 MB
  off = (off + 255) & ~(size_t)255;
  float* pre = (float*)(ws + off); off += (size_t)CH * 2048 * 4;     // 32 MB
  // total ws use ~40 MB

  (void)hipMemsetAsync(cnt, 0, (FLAG_WORD + 1) * sizeof(unsigned), stream);
  pack_kernel<<<1536, 256, 0, stream>>>(Wi, Wh_rz, Wh_n, W0p, W1p);
  prep_kernel<<<1, 128, 0, stream>>>(rstp, cnt, bucket, procmap);

  float* outp = (float*)d_out;
  float* ysp  = outp + BB * HH;
  int boff = 0;
  for (int tau = 0; tau < RCAP; ++tau) {
    const u32* seg = bucket + boff;
    const int tau0 = (tau == 0) ? 1 : 0;
    for (int c = 0; c < H_NCH[tau]; ++c) {
      int cs = c * CH;
      g1_kernel<<<512, 256, 0, stream>>>(tau0, cs, ins, rstp, h0, W0p, cnt, tau,
                                         seg, pre, ysp);
      ew0_kernel<<<512, 256, 0, stream>>>(tau0, cs, rstp, h0, cnt, tau, seg, pre,
                                          bi, bh_n, ln_s, ln_b, ysp);
      g2_kernel<<<512, 256, 0, stream>>>(cs, W1p, cnt, tau, seg, pre, ysp);
      ew1_kernel<<<512, 256, 0, stream>>>(cs, cnt, tau, seg, pre,
                                          bi, bh_n, ln_s, ln_b, ysp, outp);
    }
    boff += H_NCH[tau] * CH;
  }
  cleanup_kernel<<<BB, 256, 0, stream>>>(ins, rstp, cnt, procmap, h0, bi, bh_n,
                                         ln_s, ln_b, W0p, W1p, outp);
}